// Round 5
// baseline (209.973 us; speedup 1.0000x reference)
//
#include <hip/hip_runtime.h>
#include <hip/hip_cooperative_groups.h>
#include <math.h>

namespace cgx = cooperative_groups;

#define N_CG   50000
#define APC    13
#define FEAT   128
#define DEG    16
#define VOCAB  100
#define TPAD   16              // padded row stride of T (floats) -> 64B rows
#define ROWS_PER_BLK 16        // table rows per block-task
#define CG_PER_BLK 16          // recon cgs per block-task
#define NBLK   1024            // 4 blocks/CU * 256 CU (co-resident for grid.sync)
#define NTASK_TABLE ((VOCAB * VOCAB) / ROWS_PER_BLK)  // 625
#define NTASK_RECON (N_CG / CG_PER_BLK)               // 3125
#define PACK_TASKS  ((N_CG + 255) / 256)              // 196
#define PBLK   (VOCAB / 2)                            // 50

// ---------------- fused cooperative kernel (phases identical to R3) --------
__global__ __launch_bounds__(256, 4)
void fused_kernel(const float* __restrict__ emb,
                  const float* __restrict__ Wmsg,
                  const float* __restrict__ Wvec,
                  const float* __restrict__ xyz,
                  const int*   __restrict__ cg_z,
                  const int*   __restrict__ nbr,
                  const int*   __restrict__ ca_idx,
                  float*  __restrict__ P,
                  float4* __restrict__ xyz4,
                  float*  __restrict__ T,
                  float*  __restrict__ out) {
    cgx::grid_group grid = cgx::this_grid();
    __shared__ __align__(16) char smem[8448];   // union: table 8256B / recon 7104B

    int t = threadIdx.x;
    int b = blockIdx.x;

    // ---- Phase 0: P GEMM (blocks [0,50)) + xyz4 pack (blocks [50,246)) ----
    if (b < PBLK) {
        int z = b * 2 + (t >> 7);          // wave-uniform z
        int f = t & 127;
        float acc = 0.f;
        if (z != 0) {
            #pragma unroll 8
            for (int k = 0; k < FEAT; ++k)
                acc += emb[z * FEAT + k] * Wmsg[k * FEAT + f];
        }
        P[z * FEAT + f] = acc;
    } else if (b - PBLK < PACK_TASKS) {
        int i = (b - PBLK) * 256 + t;
        if (i < N_CG)
            xyz4[i] = make_float4(xyz[3*i], xyz[3*i+1], xyz[3*i+2],
                                  __int_as_float(cg_z[i]));
    }
    grid.sync();

    // ---- Phase 1: T tile per block (blocks [0,625)) ----
    if (b < NTASK_TABLE) {
        float (*hs)[FEAT + 1] = (float (*)[FEAT + 1])smem;
        int row0 = b * ROWS_PER_BLK;
        #pragma unroll
        for (int i = 0; i < (ROWS_PER_BLK * FEAT) / 256; ++i) {
            int v = t + i * 256;
            int r = v >> 7, f = v & 127;
            int row = row0 + r;
            int zi = row / VOCAB, zj = row % VOCAB;
            float h = P[zi * FEAT + f] + P[zj * FEAT + f];
            hs[r][f] = h / (1.f + expf(-h));   // silu
        }
        __syncthreads();
        if (t < ROWS_PER_BLK * APC) {
            int r = t / APC, c = t % APC;
            float s = 0.f;
            #pragma unroll 8
            for (int f = 0; f < FEAT; ++f)
                s += hs[r][f] * Wvec[f * APC + c];
            T[(size_t)(row0 + r) * TPAD + c] = s;
        }
    }
    grid.sync();

    // ---- Phase 2: recon, grid-strided (3125 tasks) ----
    float4 (*eu)[DEG + 1] = (float4 (*)[DEG + 1])smem;        // 4352B
    float4* xis  = (float4*)(smem + 4352);                    // 256B
    float*  obuf = (float*) (smem + 4352 + 256);              // 2496B
    for (int task = b; task < NTASK_RECON; task += NBLK) {
        int cg0 = task * CG_PER_BLK;
        {   // one edge per thread
            int g = t >> 4, k = t & 15;
            int cgi = cg0 + g;
            int e = cgi * DEG + k;             // src = repeat(arange, DEG)
            int j = nbr[2 * e + 1];
            float4 pj = xyz4[j];
            float4 pi = xyz4[cgi];
            if (k == 0) xis[g] = pi;
            float dx = pj.x - pi.x, dy = pj.y - pi.y, dz = pj.z - pi.z;
            float inv = 1.f / (sqrtf(dx*dx + dy*dy + dz*dz) + 1e-8f);
            int row = __float_as_int(pi.w) * VOCAB + __float_as_int(pj.w);
            eu[g][k] = make_float4(dx*inv, dy*inv, dz*inv, __int_as_float(row));
        }
        __syncthreads();
        if (t < CG_PER_BLK * APC) {            // one (cg, channel) per thread
            int g = t / APC, c = t % APC;
            int cgi = cg0 + g;
            float a0 = 0.f, a1 = 0.f, a2 = 0.f;
            #pragma unroll
            for (int k = 0; k < DEG; ++k) {
                float4 u = eu[g][k];
                int row = __float_as_int(u.w);
                float w = T[(size_t)row * TPAD + c];
                a0 += w * u.x; a1 += w * u.y; a2 += w * u.z;
            }
            if (c == ca_idx[cgi] - cgi * APC) { a0 = 0.f; a1 = 0.f; a2 = 0.f; }
            float4 xi = xis[g];
            obuf[t * 3 + 0] = a0 + xi.x;
            obuf[t * 3 + 1] = a1 + xi.y;
            obuf[t * 3 + 2] = a2 + xi.z;
        }
        __syncthreads();
        if (t < (CG_PER_BLK * APC * 3) / 4) {  // 156 float4, contiguous
            float4* ov = (float4*)(out + (size_t)task * (CG_PER_BLK * APC * 3));
            ov[t] = ((const float4*)obuf)[t];
        }
        __syncthreads();                       // protect eu/obuf for next task
    }
}

// ---------------- R3 fallback kernels (used only if coop launch fails) ----
__global__ void p_pack_kernel(const float* __restrict__ emb,
                              const float* __restrict__ Wmsg,
                              const float* __restrict__ xyz,
                              const int*   __restrict__ cg_z,
                              float*  __restrict__ P,
                              float4* __restrict__ xyz4) {
    int b = blockIdx.x, t = threadIdx.x;
    if (b < PBLK) {
        int z = b * 2 + (t >> 7), f = t & 127;
        float acc = 0.f;
        if (z != 0) {
            #pragma unroll 8
            for (int k = 0; k < FEAT; ++k)
                acc += emb[z * FEAT + k] * Wmsg[k * FEAT + f];
        }
        P[z * FEAT + f] = acc;
        return;
    }
    int i = (b - PBLK) * 256 + t;
    if (i < N_CG)
        xyz4[i] = make_float4(xyz[3*i], xyz[3*i+1], xyz[3*i+2],
                              __int_as_float(cg_z[i]));
}

__global__ void table_kernel(const float* __restrict__ P,
                             const float* __restrict__ Wvec,
                             float* __restrict__ T) {
    __shared__ float hs[ROWS_PER_BLK][FEAT + 1];
    int t = threadIdx.x;
    int row0 = blockIdx.x * ROWS_PER_BLK;
    #pragma unroll
    for (int i = 0; i < (ROWS_PER_BLK * FEAT) / 256; ++i) {
        int v = t + i * 256;
        int r = v >> 7, f = v & 127;
        int row = row0 + r;
        int zi = row / VOCAB, zj = row % VOCAB;
        float h = P[zi * FEAT + f] + P[zj * FEAT + f];
        hs[r][f] = h / (1.f + expf(-h));
    }
    __syncthreads();
    if (t < ROWS_PER_BLK * APC) {
        int r = t / APC, c = t % APC;
        float s = 0.f;
        #pragma unroll 8
        for (int f = 0; f < FEAT; ++f)
            s += hs[r][f] * Wvec[f * APC + c];
        T[(size_t)(row0 + r) * TPAD + c] = s;
    }
}

__global__ void recon_kernel(const float4* __restrict__ xyz4,
                             const int*    __restrict__ nbr,
                             const int*    __restrict__ ca_idx,
                             const float*  __restrict__ T,
                             float* __restrict__ out) {
    __shared__ float4 eu[CG_PER_BLK][DEG + 1];
    __shared__ float4 xis[CG_PER_BLK];
    __shared__ float  obuf[CG_PER_BLK * APC * 3];
    int t = threadIdx.x;
    int cg0 = blockIdx.x * CG_PER_BLK;
    {
        int g = t >> 4, k = t & 15;
        int cg = cg0 + g;
        int e  = cg * DEG + k;
        int j  = nbr[2 * e + 1];
        float4 pj = xyz4[j];
        float4 pi = xyz4[cg];
        if (k == 0) xis[g] = pi;
        float dx = pj.x - pi.x, dy = pj.y - pi.y, dz = pj.z - pi.z;
        float inv = 1.f / (sqrtf(dx*dx + dy*dy + dz*dz) + 1e-8f);
        int row = __float_as_int(pi.w) * VOCAB + __float_as_int(pj.w);
        eu[g][k] = make_float4(dx*inv, dy*inv, dz*inv, __int_as_float(row));
    }
    __syncthreads();
    if (t < CG_PER_BLK * APC) {
        int g = t / APC, c = t % APC;
        int cg = cg0 + g;
        float a0 = 0.f, a1 = 0.f, a2 = 0.f;
        #pragma unroll
        for (int k = 0; k < DEG; ++k) {
            float4 u = eu[g][k];
            int row = __float_as_int(u.w);
            float w = T[(size_t)row * TPAD + c];
            a0 += w * u.x; a1 += w * u.y; a2 += w * u.z;
        }
        if (c == ca_idx[cg] - cg * APC) { a0 = 0.f; a1 = 0.f; a2 = 0.f; }
        float4 xi = xis[g];
        obuf[t * 3 + 0] = a0 + xi.x;
        obuf[t * 3 + 1] = a1 + xi.y;
        obuf[t * 3 + 2] = a2 + xi.z;
    }
    __syncthreads();
    if (t < (CG_PER_BLK * APC * 3) / 4) {
        float4* ov = (float4*)(out + (size_t)blockIdx.x * (CG_PER_BLK * APC * 3));
        ov[t] = ((const float4*)obuf)[t];
    }
}

extern "C" void kernel_launch(void* const* d_in, const int* in_sizes, int n_in,
                              void* d_out, int out_size, void* d_ws, size_t ws_size,
                              hipStream_t stream) {
    const float* emb     = (const float*)d_in[1];
    const float* Wmsg    = (const float*)d_in[2];
    const float* Wvec    = (const float*)d_in[3];
    const float* cg_xyz  = (const float*)d_in[0];
    const int*   cg_z    = (const int*)d_in[4];
    const int*   nbr     = (const int*)d_in[5];
    const int*   ca_idx  = (const int*)d_in[7];
    float* out = (float*)d_out;

    float*  T    = (float*)d_ws;                                       // 640 KB
    float4* xyz4 = (float4*)((char*)d_ws + (size_t)VOCAB*VOCAB*TPAD*4); // 800 KB
    float*  P    = (float*)((char*)xyz4 + (size_t)N_CG * 16);          // 51.2 KB

    void* args[] = {(void*)&emb, (void*)&Wmsg, (void*)&Wvec, (void*)&cg_xyz,
                    (void*)&cg_z, (void*)&nbr, (void*)&ca_idx,
                    (void*)&P, (void*)&xyz4, (void*)&T, (void*)&out};
    hipError_t err = hipLaunchCooperativeKernel((const void*)fused_kernel,
                                                dim3(NBLK), dim3(256),
                                                args, 0, stream);
    if (err != hipSuccess) {   // safety net: R3's proven 3-kernel path
        p_pack_kernel<<<PBLK + PACK_TASKS, 256, 0, stream>>>(
            emb, Wmsg, cg_xyz, cg_z, P, xyz4);
        table_kernel<<<NTASK_TABLE, 256, 0, stream>>>(P, Wvec, T);
        recon_kernel<<<NTASK_RECON, 256, 0, stream>>>(xyz4, nbr, ca_idx, T, out);
    }
}

// Round 6
// 53.034 us; speedup vs baseline: 3.9592x; 3.9592x over previous
//
#include <hip/hip_runtime.h>
#include <math.h>

#define N_CG   50000
#define APC    13
#define FEAT   128
#define DEG    16
#define VOCAB  100
#define TPAD   16              // padded row stride of T (floats) -> 64B rows
#define ZJT    16              // zj rows per table block
#define NTILE  7               // ceil(VOCAB/ZJT)
#define TBLK   (VOCAB * NTILE) // 700 table blocks
#define PACKB  ((N_CG + 255) / 256)   // 196 pack blocks
#define CG_PER_BLK 16

// Kernel 1 — TWO independent roles in one launch (no intra-kernel ordering):
//  blocks [0,700):   T tile (zi, zj0..zj0+15). P rows recomputed IN-BLOCK from
//                    emb via scalar-broadcast GEMM: lanes = f, emb[z][k] is
//                    wave-uniform (s_load, free), Wmsg[k][f] coalesced vector
//                    load shared by 9 accumulators. P never materialized.
//  blocks [700,896): pack xyz4[i] = {x,y,z, bitcast(cg_z[i])}.
__global__ void table_pack_kernel(const float* __restrict__ emb,
                                  const float* __restrict__ Wmsg,
                                  const float* __restrict__ Wvec,
                                  const float* __restrict__ xyz,
                                  const int*   __restrict__ cg_z,
                                  float*  __restrict__ T,
                                  float4* __restrict__ xyz4) {
    int b = blockIdx.x, t = threadIdx.x;
    if (b >= TBLK) {                       // ---- pack role ----
        int i = (b - TBLK) * 256 + t;
        if (i < N_CG)
            xyz4[i] = make_float4(xyz[3*i], xyz[3*i+1], xyz[3*i+2],
                                  __int_as_float(cg_z[i]));
        return;
    }
    // ---- table role ----
    __shared__ float hs[ZJT][FEAT + 1];    // silu rows, padded
    int zi    = b / NTILE;
    int zj0   = (b % NTILE) * ZJT;
    int nrows = (VOCAB - zj0 < ZJT) ? (VOCAB - zj0) : ZJT;

    int f = t & 127;                       // lane's output feature
    int half = t >> 7;                     // row-half: rows [half*8, half*8+8)
    int r0 = half * 8;

    // 9 accumulators: 8 zj rows + the zi row. emb row indices are
    // block-uniform -> scalar loads.
    int zrow[9];
    #pragma unroll
    for (int i = 0; i < 8; ++i) {
        int zz = zj0 + r0 + i;
        zrow[i] = (zz < VOCAB) ? zz : (VOCAB - 1);   // clamped rows unused
    }
    zrow[8] = zi;

    float acc[9];
    #pragma unroll
    for (int i = 0; i < 9; ++i) acc[i] = 0.f;

    #pragma unroll 4
    for (int k = 0; k < FEAT; ++k) {
        float w = Wmsg[k * FEAT + f];      // coalesced; L1/L2-resident row
        #pragma unroll
        for (int i = 0; i < 9; ++i)
            acc[i] += emb[zrow[i] * FEAT + k] * w;   // wave-uniform -> s_load
    }

    // S_I[z] = emb[z] * (z != 0): zero rule applied to P rows.
    float pzi = (zi != 0) ? acc[8] : 0.f;
    #pragma unroll
    for (int i = 0; i < 8; ++i) {
        int r = r0 + i;
        float pz = (zrow[i] != 0) ? acc[i] : 0.f;
        float h = pzi + pz;
        hs[r][f] = h / (1.f + expf(-h));   // silu
    }
    __syncthreads();

    if (t < nrows * APC) {
        int r = t / APC, c = t % APC;
        float s = 0.f;
        #pragma unroll 8
        for (int ff = 0; ff < FEAT; ++ff)
            s += hs[r][ff] * Wvec[ff * APC + c];     // Wvec 6.5KB, L1-resident
        T[(size_t)(zi * VOCAB + zj0 + r) * TPAD + c] = s;
    }
}

// Kernel 2 — fused segment-sum + reconstruction. IDENTICAL to R3's recon.
__global__ void recon_kernel(const float4* __restrict__ xyz4,
                             const int*    __restrict__ nbr,
                             const int*    __restrict__ ca_idx,
                             const float*  __restrict__ T,
                             float* __restrict__ out) {
    __shared__ float4 eu[CG_PER_BLK][DEG + 1];     // padded: conflict-free
    __shared__ float4 xis[CG_PER_BLK];
    __shared__ float  obuf[CG_PER_BLK * APC * 3];  // 624 floats

    int t = threadIdx.x;
    int cg0 = blockIdx.x * CG_PER_BLK;

    {   // phase 1: one edge per thread
        int g = t >> 4, k = t & 15;
        int cg = cg0 + g;
        int e  = cg * DEG + k;             // src = repeat(arange(N_CG), DEG)
        int j  = nbr[2 * e + 1];
        float4 pj = xyz4[j];
        float4 pi = xyz4[cg];
        if (k == 0) xis[g] = pi;
        float dx = pj.x - pi.x, dy = pj.y - pi.y, dz = pj.z - pi.z;
        float inv = 1.f / (sqrtf(dx*dx + dy*dy + dz*dz) + 1e-8f);
        int row = __float_as_int(pi.w) * VOCAB + __float_as_int(pj.w);
        eu[g][k] = make_float4(dx*inv, dy*inv, dz*inv, __int_as_float(row));
    }
    __syncthreads();

    if (t < CG_PER_BLK * APC) {            // phase 2
        int g = t / APC, c = t % APC;
        int cg = cg0 + g;
        float a0 = 0.f, a1 = 0.f, a2 = 0.f;
        #pragma unroll
        for (int k = 0; k < DEG; ++k) {
            float4 u = eu[g][k];
            int row = __float_as_int(u.w);
            float w = T[(size_t)row * TPAD + c];
            a0 += w * u.x; a1 += w * u.y; a2 += w * u.z;
        }
        // ca atom: channel = ca_idx[cg] - first, first = cg*APC
        if (c == ca_idx[cg] - cg * APC) { a0 = 0.f; a1 = 0.f; a2 = 0.f; }
        float4 xi = xis[g];
        obuf[t * 3 + 0] = a0 + xi.x;
        obuf[t * 3 + 1] = a1 + xi.y;
        obuf[t * 3 + 2] = a2 + xi.z;
    }
    __syncthreads();

    if (t < (CG_PER_BLK * APC * 3) / 4) {  // 156 float4, contiguous 2496B
        float4* ov = (float4*)(out + (size_t)blockIdx.x * (CG_PER_BLK * APC * 3));
        ov[t] = ((const float4*)obuf)[t];
    }
}

extern "C" void kernel_launch(void* const* d_in, const int* in_sizes, int n_in,
                              void* d_out, int out_size, void* d_ws, size_t ws_size,
                              hipStream_t stream) {
    const float* cg_xyz  = (const float*)d_in[0];
    const float* emb     = (const float*)d_in[1];
    const float* W_msg   = (const float*)d_in[2];
    const float* W_vec   = (const float*)d_in[3];
    const int*   cg_z    = (const int*)d_in[4];
    const int*   nbr     = (const int*)d_in[5];
    const int*   ca_idx  = (const int*)d_in[7];
    float* out = (float*)d_out;

    float*  T    = (float*)d_ws;                                   // 640 KB
    float4* xyz4 = (float4*)((char*)d_ws + (size_t)VOCAB*VOCAB*TPAD*4);

    table_pack_kernel<<<TBLK + PACKB, 256, 0, stream>>>(
        emb, W_msg, W_vec, cg_xyz, cg_z, T, xyz4);
    recon_kernel<<<N_CG / CG_PER_BLK, 256, 0, stream>>>(
        xyz4, nbr, ca_idx, T, out);
}

// Round 7
// 37.112 us; speedup vs baseline: 5.6579x; 1.4290x over previous
//
#include <hip/hip_runtime.h>
#include <math.h>

#define N_CG   50000
#define APC    13
#define FEAT   128
#define DEG    16
#define VOCAB  100
#define TPAD   16              // padded row stride of T (floats) -> 64B rows
#define ZJT    16              // zj rows per table block
#define NTILE  7               // ceil(VOCAB/ZJT)
#define TBLK   (VOCAB * NTILE) // 700 table blocks
#define PACKB  ((N_CG + 255) / 256)   // 196 pack blocks
#define CG_PER_BLK 16

// Kernel 1 — two independent roles:
//  blocks [0,700):   T tile (zi, zj = zj0..zj0+15). The <=17 needed P rows are
//                    recomputed in-block, but with the latency fix vs R5:
//                    emb rows are STAGED INTO LDS first (coalesced), then the
//                    9-accumulator GEMM reads them as ds_read_b128 BROADCASTS
//                    (conflict-free, ~120cy latency, pipelined) while Wmsg
//                    streams from global coalesced with vmcnt pipelining.
//  blocks [700,896): pack xyz4[i] = {x,y,z, bitcast(cg_z[i])}.
__global__ void table_pack_kernel(const float* __restrict__ emb,
                                  const float* __restrict__ Wmsg,
                                  const float* __restrict__ Wvec,
                                  const float* __restrict__ xyz,
                                  const int*   __restrict__ cg_z,
                                  float*  __restrict__ T,
                                  float4* __restrict__ xyz4) {
    int b = blockIdx.x, t = threadIdx.x;
    if (b >= TBLK) {                       // ---- pack role ----
        int i = (b - TBLK) * 256 + t;
        if (i < N_CG)
            xyz4[i] = make_float4(xyz[3*i], xyz[3*i+1], xyz[3*i+2],
                                  __int_as_float(cg_z[i]));
        return;
    }
    // ---- table role ----
    __shared__ __align__(16) float emb_lds[ZJT + 1][FEAT];  // rows 0..15: zj, 16: zi
    __shared__ float hs[ZJT][FEAT + 1];                     // silu rows (padded)

    int zi    = b / NTILE;
    int zj0   = (b % NTILE) * ZJT;
    int nrows = (VOCAB - zj0 < ZJT) ? (VOCAB - zj0) : ZJT;

    // Stage 17 emb rows into LDS, coalesced (k fastest).
    for (int i = t; i < (ZJT + 1) * FEAT; i += 256) {
        int r = i >> 7, k = i & 127;
        int z = (r == ZJT) ? zi : (zj0 + r);
        if (z >= VOCAB) z = 0;             // OOB rows staged but never used
        emb_lds[r][k] = emb[z * FEAT + k];
    }
    __syncthreads();

    int f = t & 127;                       // lane's output feature (coalesced)
    int half = t >> 7;
    int rbase = half * 8;                  // this thread: rows rbase..rbase+7 + zi

    float acc[9];
    #pragma unroll
    for (int i = 0; i < 9; ++i) acc[i] = 0.f;

    // GEMM: 4 k's per group; Wmsg = coalesced global stream (pipelined),
    // emb = LDS b128 broadcast (conflict-free).
    #pragma unroll 2
    for (int k0 = 0; k0 < FEAT; k0 += 4) {
        float w0 = Wmsg[(k0 + 0) * FEAT + f];
        float w1 = Wmsg[(k0 + 1) * FEAT + f];
        float w2 = Wmsg[(k0 + 2) * FEAT + f];
        float w3 = Wmsg[(k0 + 3) * FEAT + f];
        #pragma unroll
        for (int i = 0; i < 9; ++i) {
            int r = (i < 8) ? (rbase + i) : ZJT;
            float4 e = *(const float4*)&emb_lds[r][k0];
            acc[i] += e.x * w0 + e.y * w1 + e.z * w2 + e.w * w3;
        }
    }

    // zero-rule (S_I[z]=0 for z==0) + silu; write hs rows.
    float pzi = (zi != 0) ? acc[8] : 0.f;
    #pragma unroll
    for (int i = 0; i < 8; ++i) {
        int r = rbase + i;
        int zj = zj0 + r;
        float pz = (zj != 0 && zj < VOCAB) ? acc[i] : 0.f;
        float h = pzi + pz;
        hs[r][f] = h / (1.f + expf(-h));   // silu
    }
    __syncthreads();

    if (t < nrows * APC) {
        int r = t / APC, c = t % APC;
        float s = 0.f;
        #pragma unroll 8
        for (int ff = 0; ff < FEAT; ++ff)
            s += hs[r][ff] * Wvec[ff * APC + c];     // Wvec 6.5KB, L1-resident
        T[(size_t)(zi * VOCAB + zj0 + r) * TPAD + c] = s;
    }
}

// Kernel 2 — fused segment-sum + reconstruction (R3's measured-good recon;
// only change: int2 nbr load instead of stride-2 scalar).
__global__ void recon_kernel(const float4* __restrict__ xyz4,
                             const int*    __restrict__ nbr,
                             const int*    __restrict__ ca_idx,
                             const float*  __restrict__ T,
                             float* __restrict__ out) {
    __shared__ float4 eu[CG_PER_BLK][DEG + 1];     // padded: conflict-free
    __shared__ float4 xis[CG_PER_BLK];
    __shared__ float  obuf[CG_PER_BLK * APC * 3];  // 624 floats

    int t = threadIdx.x;
    int cg0 = blockIdx.x * CG_PER_BLK;

    {   // phase 1: one edge per thread
        int g = t >> 4, k = t & 15;
        int cg = cg0 + g;
        int e  = cg * DEG + k;             // src = repeat(arange(N_CG), DEG)
        int2 ed = ((const int2*)nbr)[e];   // {src, dst} in one 8B load
        int j = ed.y;
        float4 pj = xyz4[j];
        float4 pi = xyz4[cg];
        if (k == 0) xis[g] = pi;
        float dx = pj.x - pi.x, dy = pj.y - pi.y, dz = pj.z - pi.z;
        float inv = 1.f / (sqrtf(dx*dx + dy*dy + dz*dz) + 1e-8f);
        int row = __float_as_int(pi.w) * VOCAB + __float_as_int(pj.w);
        eu[g][k] = make_float4(dx*inv, dy*inv, dz*inv, __int_as_float(row));
    }
    __syncthreads();

    if (t < CG_PER_BLK * APC) {            // phase 2
        int g = t / APC, c = t % APC;
        int cg = cg0 + g;
        float a0 = 0.f, a1 = 0.f, a2 = 0.f;
        #pragma unroll
        for (int k = 0; k < DEG; ++k) {
            float4 u = eu[g][k];
            int row = __float_as_int(u.w);
            float w = T[(size_t)row * TPAD + c];
            a0 += w * u.x; a1 += w * u.y; a2 += w * u.z;
        }
        // ca atom: channel = ca_idx[cg] - first, first = cg*APC
        if (c == ca_idx[cg] - cg * APC) { a0 = 0.f; a1 = 0.f; a2 = 0.f; }
        float4 xi = xis[g];
        obuf[t * 3 + 0] = a0 + xi.x;
        obuf[t * 3 + 1] = a1 + xi.y;
        obuf[t * 3 + 2] = a2 + xi.z;
    }
    __syncthreads();

    if (t < (CG_PER_BLK * APC * 3) / 4) {  // 156 float4, contiguous 2496B
        float4* ov = (float4*)(out + (size_t)blockIdx.x * (CG_PER_BLK * APC * 3));
        ov[t] = ((const float4*)obuf)[t];
    }
}

extern "C" void kernel_launch(void* const* d_in, const int* in_sizes, int n_in,
                              void* d_out, int out_size, void* d_ws, size_t ws_size,
                              hipStream_t stream) {
    const float* cg_xyz  = (const float*)d_in[0];
    const float* emb     = (const float*)d_in[1];
    const float* W_msg   = (const float*)d_in[2];
    const float* W_vec   = (const float*)d_in[3];
    const int*   cg_z    = (const int*)d_in[4];
    const int*   nbr     = (const int*)d_in[5];
    const int*   ca_idx  = (const int*)d_in[7];
    float* out = (float*)d_out;

    float*  T    = (float*)d_ws;                                   // 640 KB
    float4* xyz4 = (float4*)((char*)d_ws + (size_t)VOCAB*VOCAB*TPAD*4);

    table_pack_kernel<<<TBLK + PACKB, 256, 0, stream>>>(
        emb, W_msg, W_vec, cg_xyz, cg_z, T, xyz4);
    recon_kernel<<<N_CG / CG_PER_BLK, 256, 0, stream>>>(
        xyz4, nbr, ca_idx, T, out);
}